// Round 10
// baseline (1586.832 us; speedup 1.0000x reference)
//
#include <hip/hip_runtime.h>
#include <hip/hip_cooperative_groups.h>
#include <math.h>

namespace cg = cooperative_groups;

#define NIx 32
#define NOx 2
#define NUx 10
#define NHx 1024
#define NBx 16384
#define MIx 138
#define EPSQ 1e-4f
#define BNEPS 1e-5f
#define ITERS 30
#define SLOPE 0.2f
#define SIGMA_C 0.1f

// workspace layout (float offsets). Max = 174400 floats = 697.6 KB (< proven 723 KB).
#define QM_OFF 0        // 120 (pad 128)
#define G_OFF 128       // 144 x 12 -> 1856
#define H_OFF 1856      // 144 (pad 2048)
#define P2_OFF 2048     // 16 bufs x 20 (sum[10],sq[10]) = 320 (pad 2368)
#define P1S_OFF 2368    // 4 bufs x 1024 col-sums
#define P1Q_OFF 6464    // 4 bufs x 1024 col-sumsq -> 10560
#define PRAW_OFF 10560  // 16384 x 10 -> 174400
// memset zeroes [P2_OFF, P1Q_OFF+4096) = floats 2048..10560

// ======================= CONFIGURATION LEDGER (rounds 0-9) =======================
// r9 baseline = 308.6 us (k_ipm 174 + non-ipm 135). Laws:
//   * k_ipm: 128-VGPR envelope (r2 promotion-spill, r8 cap-spill); 8 lanes/elem
//     optimal; VALU-issue bound @78%; ~174 us structural floor.
//   * Reuse law (r6): occupancy gains must never multiply DRAM traffic.
//   * Cap law (r8): never set min-waves bounds below natural VGPR pressure.
//   * v_pk_*_f32 issue-neutral (r1). s_load == LDS-broadcast for uniform (r3/r4).
// ROUND 10: BN1-stats + fc2 both computed FC1 (537M MACs each) — fused into one
// cooperative kernel holding h in registers across grid.sync(). Eliminates the
// duplicate GEMM + one launch. QP-build appended to block 255's tail.
// =================================================================================

__device__ __forceinline__ float frcp(float x){ return __builtin_amdgcn_rcpf(x); }
__device__ __forceinline__ float frsq(float x){ return __builtin_amdgcn_rsqf(x); }
__device__ __forceinline__ float lrelu(float x){ return x > 0.0f ? x : SLOPE * x; }

typedef float v2f __attribute__((ext_vector_type(2)));
__device__ __forceinline__ v2f make2(float a, float b){ v2f r; r.x = a; r.y = b; return r; }
__device__ __forceinline__ v2f splat2(float a){ v2f r; r.x = a; r.y = a; return r; }
__device__ __forceinline__ v2f pkfma(v2f a, v2f b, v2f c){ return __builtin_elementwise_fma(a, b, c); }
__device__ __forceinline__ v2f pkmax(v2f a, v2f b){ return __builtin_elementwise_max(a, b); }

// ---- DPP cross-lane reductions (VALU, no LDS pipe) ----
template<int CTRL>
__device__ __forceinline__ float dpp_mov(float x){
    int y = __builtin_amdgcn_update_dpp(0, __float_as_int(x), CTRL, 0xF, 0xF, true);
    return __int_as_float(y);
}
__device__ __forceinline__ float red8_add(float x){
    x += dpp_mov<0xB1>(x);
    x += dpp_mov<0x4E>(x);
    x += dpp_mov<0x141>(x);
    return x;
}
__device__ __forceinline__ float red8_max(float x){
    x = fmaxf(x, dpp_mov<0xB1>(x));
    x = fmaxf(x, dpp_mov<0x4E>(x));
    x = fmaxf(x, dpp_mov<0x141>(x));
    return x;
}

// ---------- fused FC1 + BN1-stats + grid.sync + BN1-apply + FC2 (+ QP tail) ----------
// 256 blocks x 1024 threads (cooperative, 1 block/CU). Thread t: row = bid*64+(t&63),
// k-slice q = t>>6 (cols {ch*128 + q*8 + i}). h kept in 64 registers across the sync.
__global__ __launch_bounds__(1024) void k_fused(const float* __restrict__ x, const float* __restrict__ w1,
                                                const float* __restrict__ w2, const float* __restrict__ b1v,
                                                const float* __restrict__ b2v, const float* __restrict__ g1,
                                                const float* __restrict__ bb1,
                                                const float* __restrict__ L, const float* __restrict__ LP,
                                                const float* __restrict__ LR, const float* __restrict__ A,
                                                const float* __restrict__ Bm, const float* __restrict__ u0,
                                                const float* __restrict__ s0, float* __restrict__ ws){
    __shared__ __align__(16) float sW[4096];    // 16 KB w1 chunk
    __shared__ float sA1[1024], sC1[1024];
    __shared__ float pacc[10240];               // 40 KB
    // QP-build arrays (block 255 tail only; LDS total ~97 KB, 1 block/CU fine)
    __shared__ float sL[1024], sLP[1024], sAq[1024], sQ[1024], sP[1024];
    __shared__ float sPow[4][64];
    __shared__ float sBh[1280];
    __shared__ float sQB[1280];
    __shared__ float sR[3];

    int t = threadIdx.x;
    int r = t & 63;
    int q = t >> 6;                  // 0..15
    int row = blockIdx.x * 64 + r;

    // ---- phase 1: raw h for this block's 64 rows, kept in registers ----
    const float4* xg4 = (const float4*)(x + (size_t)row * 32);
    float4 xr[8];
    #pragma unroll
    for (int i = 0; i < 8; ++i) xr[i] = xg4[i];
    float h[64];
    const float4* w1g4 = (const float4*)w1;
    float4* sW4 = (float4*)sW;
    #pragma unroll
    for (int ch = 0; ch < 8; ++ch){
        __syncthreads();
        sW4[t] = w1g4[ch*1024 + t];
        __syncthreads();
        #pragma unroll
        for (int i = 0; i < 8; ++i){
            int klc = q*8 + i;                 // wave-uniform
            int kl  = ch*128 + klc;
            const float4* wv4 = sW4 + klc*8;   // 64-lane broadcast ds_read_b128
            float a0 = 0, a1 = 0, a2 = 0, a3 = 0;
            #pragma unroll
            for (int u = 0; u < 8; ++u){
                float4 wv = wv4[u];
                float4 xv = xr[u];
                a0 = fmaf(xv.x, wv.x, a0);
                a1 = fmaf(xv.y, wv.y, a1);
                a2 = fmaf(xv.z, wv.z, a2);
                a3 = fmaf(xv.w, wv.w, a3);
            }
            h[ch*8 + i] = lrelu((a0 + a1) + (a2 + a3) + b1v[kl]);
        }
    }
    // ---- per-wave column stats: reduce over 64 rows (lanes), atomics into P1 bufs ----
    {
        int buf = (blockIdx.x & 3) * 1024;
        #pragma unroll
        for (int u = 0; u < 64; ++u){
            float hv = h[u];
            float s = hv, sq = hv*hv;
            #pragma unroll
            for (int m = 1; m < 64; m <<= 1){
                s  += __shfl_xor(s, m);
                sq += __shfl_xor(sq, m);
            }
            if (r == 0){
                int kl = (u >> 3)*128 + q*8 + (u & 7);
                atomicAdd(&ws[P1S_OFF + buf + kl], s);
                atomicAdd(&ws[P1Q_OFF + buf + kl], sq);
            }
        }
    }
    __threadfence();
    cg::this_grid().sync();
    // ---- finalize BN1 stats (each block, col t) ----
    {
        float ssum = 0.0f, qsum = 0.0f;
        #pragma unroll
        for (int b = 0; b < 4; ++b){
            ssum += ws[P1S_OFF + b*1024 + t];
            qsum += ws[P1Q_OFF + b*1024 + t];
        }
        float mu  = ssum * (1.0f/16384.0f);
        float var = qsum * (1.0f/16384.0f) - mu*mu;
        float a1 = g1[t] / sqrtf(var + BNEPS);
        sA1[t] = a1;
        sC1[t] = bb1[t] - mu * a1;
    }
    __syncthreads();
    // ---- phase 2: BN-apply + w2 matmul on register-resident h ----
    float acc[10];
    #pragma unroll
    for (int j = 0; j < 10; ++j) acc[j] = 0.0f;
    #pragma unroll
    for (int ch = 0; ch < 8; ++ch){
        #pragma unroll
        for (int i = 0; i < 8; ++i){
            int kl = ch*128 + q*8 + i;         // wave-uniform
            float hn = fmaf(h[ch*8 + i], sA1[kl], sC1[kl]);
            #pragma unroll
            for (int j = 0; j < 10; ++j) acc[j] = fmaf(hn, w2[j*1024 + kl], acc[j]);
        }
    }
    #pragma unroll
    for (int j = 0; j < 10; ++j) pacc[t*10 + j] = acc[j];
    __syncthreads();
    if (t < 64){
        float pv[10];
        #pragma unroll
        for (int j = 0; j < 10; ++j){
            float a = b2v[j];
            #pragma unroll
            for (int w = 0; w < 16; ++w) a += pacc[(w*64 + t)*10 + j];
            pv[j] = lrelu(a);
        }
        #pragma unroll
        for (int j = 0; j < 10; ++j) ws[PRAW_OFF + (size_t)(blockIdx.x*64 + t)*10 + j] = pv[j];
        float sv[10], qv[10];
        #pragma unroll
        for (int j = 0; j < 10; ++j){ sv[j] = pv[j]; qv[j] = pv[j]*pv[j]; }
        #pragma unroll
        for (int m = 1; m < 64; m <<= 1){
            #pragma unroll
            for (int j = 0; j < 10; ++j){
                sv[j] += __shfl_xor(sv[j], m);
                qv[j] += __shfl_xor(qv[j], m);
            }
        }
        if (t == 0){
            int base = P2_OFF + (blockIdx.x & 15) * 20;
            #pragma unroll
            for (int j = 0; j < 10; ++j){
                atomicAdd(&ws[base + j], sv[j]);
                atomicAdd(&ws[base + 10 + j], qv[j]);
            }
        }
    }
    // ---- QP-build tail (block 255 only; block-local barriers are legal) ----
    if (blockIdx.x != 255) return;
    for (int idx = t; idx < 1024; idx += 1024){
        int i = idx >> 5, j = idx & 31;
        sL[idx]  = (j <= i) ? L[idx]  : 0.0f;
        sLP[idx] = (j <= i) ? LP[idx] : 0.0f;
        sAq[idx] = A[idx];
    }
    if (t < 64) sPow[0][t] = Bm[t];
    if (t == 0){
        float a = LR[0], b = LR[2], c = LR[3];   // tril: [[a,0],[b,c]]
        sR[0] = a*a + EPSQ; sR[1] = a*b; sR[2] = b*b + c*c + EPSQ;
    }
    __syncthreads();
    for (int idx = t; idx < 1024; idx += 1024){
        int i = idx >> 5, j = idx & 31;
        float qv = 0.0f, pv = 0.0f;
        for (int k = 0; k < 32; ++k){
            qv = fmaf(sL[i*32+k],  sL[j*32+k],  qv);
            pv = fmaf(sLP[i*32+k], sLP[j*32+k], pv);
        }
        if (i == j){ qv += EPSQ; pv += EPSQ; }
        sQ[idx] = qv; sP[idx] = pv;
    }
    for (int kp = 1; kp < 4; ++kp){
        __syncthreads();
        if (t < 64){
            int i = t >> 1, c = t & 1;
            float a = 0.0f;
            for (int j = 0; j < 32; ++j) a = fmaf(sAq[i*32+j], sPow[kp-1][j*2+c], a);
            sPow[kp][t] = a;
        }
    }
    __syncthreads();
    for (int idx = t; idx < 1280; idx += 1024){
        int rr = idx / 10, c = idx % 10;
        int bi = rr >> 5, ri = rr & 31, bj = c >> 1, cj = c & 1;
        sBh[idx] = (bj <= bi) ? sPow[bi-bj][ri*2+cj] : 0.0f;
    }
    __syncthreads();
    for (int idx = t; idx < 1280; idx += 1024){
        int rr = idx / 10, c = idx % 10;
        int bi = rr >> 5, ri = rr & 31;
        const float* Qd = (bi < 3) ? sQ : sP;
        float a = 0.0f;
        for (int k = 0; k < 32; ++k) a = fmaf(Qd[ri*32+k], sBh[(bi*32+k)*10+c], a);
        sQB[idx] = a;
    }
    __syncthreads();
    if (t < 120){
        int i = t / 12, j = t % 12;
        float a = 0.0f;
        if (j < 10){
            for (int rr = 0; rr < 128; ++rr) a = fmaf(sBh[rr*10+i], sQB[rr*10+j], a);
            if ((i >> 1) == (j >> 1)) a += sR[(i&1)+(j&1)];
        }
        ws[QM_OFF + t] = a;
    }
    for (int idx = t; idx < 144*12; idx += 1024){
        int m = idx / 12, i = idx % 12;
        float v = 0.0f;
        if (i < 10 && m < MIx) v = (m < 10) ? ((i == m) ? 1.0f : 0.0f) : sBh[(m-10)*10 + i];
        ws[G_OFF + idx] = v;
    }
    for (int m = t; m < 144; m += 1024){
        float hv = 0.0f;
        if (m < MIx){
            hv = s0[m];
            if (m < 10) hv += u0[m];
            else { for (int i = 0; i < 10; ++i) hv = fmaf(sBh[(m-10)*10+i], u0[i], hv); }
        }
        ws[H_OFF + m] = hv;
    }
}

// ---------- batched IPM: 8 lanes/element, 8 elements per 64-thread block ----------
#define TIX(i,j) ((i)*((i)+1)/2 + (j))

#define PSTEPA(P, B, GP) { \
    v2f sv = s2[P], lv = lam2[P]; \
    v2f isv; isv.x = frcp(sv.x); isv.y = frcp(sv.y); \
    v2f wv = lv * isv; \
    v2f r = sv - *(const v2f*)(sHH2 + (P)*16 + lg*2); \
    _Pragma("unroll") \
    for (int _i = 0; _i < (B); ++_i) r = pkfma(splat2(z[_i]), GP[_i], r); \
    rp2[P] = r; \
    sl2 = pkfma(sv, lv, sl2); \
    _Pragma("unroll") \
    for (int _i = 0; _i < (B); ++_i){ \
        v2f wg = wv * GP[_i]; \
        _Pragma("unroll") \
        for (int _j = 0; _j <= _i; ++_j) Hm2[TIX(_i,_j)] = pkfma(wg, GP[_j], Hm2[TIX(_i,_j)]); \
    } }

#define PSTEPB(P, B, GP) { \
    v2f sv = s2[P], lv = lam2[P]; \
    v2f isv; isv.x = frcp(sv.x); isv.y = frcp(sv.y); \
    v2f coef = pkfma(lv, rp2[P], smu2) * isv; \
    _Pragma("unroll") \
    for (int _i = 0; _i < (B); ++_i) racc2[_i] = pkfma(coef, GP[_i], racc2[_i]); }

#define PSTEPC(P, B, GP) { \
    v2f dotv = splat2(0.0f); \
    _Pragma("unroll") \
    for (int _i = 0; _i < (B); ++_i) dotv = pkfma(splat2(dz[_i]), GP[_i], dotv); \
    v2f sv = s2[P], lv = lam2[P]; \
    v2f isv; isv.x = frcp(sv.x); isv.y = frcp(sv.y); \
    v2f dsv = -(rp2[P] + dotv); \
    v2f rcv = pkfma(sv, lv, nsmu2); \
    v2f dlv = -(pkfma(lv, dsv, rcv) * isv); \
    ds2[P] = dsv; dl2[P] = dlv; \
    v2f ilv; ilv.x = frcp(lv.x); ilv.y = frcp(lv.y); \
    av2 = pkmax(av2, pkmax((-dsv)*isv, (-dlv)*ilv)); }

#define LOADP(GP, PP) v2f GP[8]; { \
    const float4* _g4 = (const float4*)(sG3 + lg*36 + (PP)*16); \
    float4 _a = _g4[0], _b = _g4[1], _c = _g4[2], _d = _g4[3]; \
    GP[0] = make2(_a.x,_a.y); GP[1] = make2(_a.z,_a.w); \
    GP[2] = make2(_b.x,_b.y); GP[3] = make2(_b.z,_b.w); \
    GP[4] = make2(_c.x,_c.y); GP[5] = make2(_c.z,_c.w); \
    GP[6] = make2(_d.x,_d.y); GP[7] = make2(_d.z,_d.w); }

__global__ __launch_bounds__(64, 2) void k_ipm(const float* __restrict__ ws, const float* __restrict__ g2v,
                                               const float* __restrict__ bb2, float* __restrict__ out){
    __shared__ __align__(16) float sQm[120];
    __shared__ __align__(16) float sQt2[72];    // {Q/8, 0} interleaved, tri rows 0..7
    __shared__ __align__(16) float sPV[8*12];
    __shared__ __align__(16) float sG3[8*36];   // B=8 G pairs, pair-packed per lg
    __shared__ __align__(16) float sHH2[128];   // h pair-packed: [p*16 + lg*2 + c]
    __shared__ float sA2[10], sC2[10];
    int t = threadIdx.x;
    for (int i = t; i < 120; i += 64) sQm[i] = ws[QM_OFF + i];
    if (t < 36){
        int i = 0;
        #pragma unroll
        for (int r = 1; r < 8; ++r) if (TIX(r,0) <= t) i = r;
        int j = t - TIX(i,0);
        sQt2[t*2]   = ws[QM_OFF + i*12 + j] * 0.125f;
        sQt2[t*2+1] = 0.0f;
    }
    if (t < 10){   // BN2 finalize (redundant per block — trivial)
        float ssum = 0.0f, qsum = 0.0f;
        #pragma unroll
        for (int b = 0; b < 16; ++b){
            ssum += ws[P2_OFF + b*20 + t];
            qsum += ws[P2_OFF + b*20 + 10 + t];
        }
        float mu  = ssum * (1.0f/16384.0f);
        float var = qsum * (1.0f/16384.0f) - mu*mu;
        float a2 = g2v[t] / sqrtf(var + BNEPS);
        sA2[t] = a2;
        sC2[t] = bb2[t] - mu * a2;
    }
    __syncthreads();

    int lg = t & 7;
    int eidx = t >> 3;
    int elem = blockIdx.x * 8 + eidx;
    const float* GB = ws + G_OFF;
    const float4* sQm4 = (const float4*)sQm;

    for (int i = t; i < 80; i += 64){
        int e = i / 10, c = i - e*10;
        int el = blockIdx.x * 8 + e;
        sPV[e*12 + c] = fmaf(ws[PRAW_OFF + (size_t)el*10 + c], sA2[c], sC2[c]);
    }
    for (int i = t; i < 128; i += 64){
        int c = i & 1, lgx = (i >> 1) & 7, p = i >> 4;
        int row = 10 + (p >> 1)*32 + (2*(p & 1) + c)*8 + lgx;
        sHH2[p*16 + lgx*2 + c] = ws[H_OFF + row];
    }
    for (int i = t; i < 256; i += 64){
        int c = i & 1, ii = (i >> 1) & 7, pp = (i >> 4) & 1, lgx = i >> 5;
        int row = 106 + (pp*2 + c)*8 + lgx;
        sG3[lgx*36 + pp*16 + ii*2 + c] = GB[row*12 + ii];
    }
    v2f g0[2], g1[2], g2r[4], g3r[4], g4r[6], g5r[6];
    {
        int ra, rb;
        ra = 10 + lg; rb = 18 + lg;
        #pragma unroll
        for (int i = 0; i < 2; ++i) g0[i] = make2(GB[ra*12+i], GB[rb*12+i]);
        ra = 26 + lg; rb = 34 + lg;
        #pragma unroll
        for (int i = 0; i < 2; ++i) g1[i] = make2(GB[ra*12+i], GB[rb*12+i]);
        ra = 42 + lg; rb = 50 + lg;
        #pragma unroll
        for (int i = 0; i < 4; ++i) g2r[i] = make2(GB[ra*12+i], GB[rb*12+i]);
        ra = 58 + lg; rb = 66 + lg;
        #pragma unroll
        for (int i = 0; i < 4; ++i) g3r[i] = make2(GB[ra*12+i], GB[rb*12+i]);
        ra = 74 + lg; rb = 82 + lg;
        #pragma unroll
        for (int i = 0; i < 6; ++i) g4r[i] = make2(GB[ra*12+i], GB[rb*12+i]);
        ra = 90 + lg; rb = 98 + lg;
        #pragma unroll
        for (int i = 0; i < 6; ++i) g5r[i] = make2(GB[ra*12+i], GB[rb*12+i]);
    }
    float h16 = ws[H_OFF + lg];                          // identity rows 0..7
    float h17 = (lg < 2) ? ws[H_OFF + 8 + lg] : 1.0f;    // identity rows 8,9
    __syncthreads();

    float z[10];
    #pragma unroll
    for (int i = 0; i < 10; ++i) z[i] = 0.0f;
    v2f s2[8], lam2[8];
    #pragma unroll
    for (int p = 0; p < 8; ++p){ s2[p] = splat2(1.0f); lam2[p] = splat2(1.0f); }
    float s16v = 1.0f, s17v = 1.0f, lam16v = 1.0f;
    float lam17v = (lg < 2) ? 1.0f : 0.0f;

    #pragma unroll 1
    for (int it = 0; it < ITERS; ++it){
        v2f Hm2[36];
        {
            const v2f* qt2 = (const v2f*)sQt2;
            #pragma unroll
            for (int i = 0; i < 36; ++i) Hm2[i] = qt2[i];   // {Q/8, 0}
        }
        v2f sl2 = splat2(0.0f);
        v2f rp2[8];
        float rp16, rp17;
        PSTEPA(0, 2, g0)  PSTEPA(1, 2, g1)
        PSTEPA(2, 4, g2r) PSTEPA(3, 4, g3r)
        PSTEPA(4, 6, g4r) PSTEPA(5, 6, g5r)
        { LOADP(gv, 0) PSTEPA(6, 8, gv) }
        { LOADP(gv, 1) PSTEPA(7, 8, gv) }
        float w16, w17, sl_s;
        {
            float zs = z[0];
            #pragma unroll
            for (int i = 1; i < 8; ++i) zs = (lg == i) ? z[i] : zs;
            rp16 = zs + s16v - h16;
            sl_s = s16v * lam16v;
            w16 = lam16v * frcp(s16v);
            float zs17 = (lg == 1) ? z[9] : z[8];
            rp17 = zs17 + s17v - h17;
            sl_s = fmaf(s17v, lam17v, sl_s);
            w17 = lam17v * frcp(s17v);
        }
        float Hm[55];
        #pragma unroll
        for (int i = 0; i < 36; ++i) Hm[i] = Hm2[i].x + Hm2[i].y;
        #pragma unroll
        for (int i = 0; i < 8; ++i) Hm[TIX(i,i)] += (lg == i) ? w16 : 0.0f;
        float d88 = (lg == 0) ? w17 : 0.0f;
        float d99 = (lg == 1) ? w17 : 0.0f;
        float sl = sl2.x + sl2.y + sl_s;
        #pragma unroll
        for (int i = 0; i < 36; ++i) Hm[i] = red8_add(Hm[i]);
        d88 = red8_add(d88);
        d99 = red8_add(d99);
        sl = red8_add(sl);
        float smu = SIGMA_C * sl * (1.0f/138.0f);
        __asm__ __volatile__("" ::: "memory");
        v2f smu2 = splat2(smu);
        v2f racc2[8];
        #pragma unroll
        for (int i = 0; i < 8; ++i) racc2[i] = splat2(0.0f);
        PSTEPB(0, 2, g0)  PSTEPB(1, 2, g1)
        PSTEPB(2, 4, g2r) PSTEPB(3, 4, g3r)
        PSTEPB(4, 6, g4r) PSTEPB(5, 6, g5r)
        { LOADP(gv, 0) PSTEPB(6, 8, gv) }
        { LOADP(gv, 1) PSTEPB(7, 8, gv) }
        float coef16 = frcp(s16v) * fmaf(lam16v, rp16, smu);
        float coef17 = frcp(s17v) * fmaf(lam17v, rp17, smu);
        coef17 = (lg < 2) ? coef17 : 0.0f;
        float rs[10];
        #pragma unroll
        for (int i = 0; i < 8; ++i){
            float v = racc2[i].x + racc2[i].y;
            v += (lg == i) ? coef16 : 0.0f;
            rs[i] = red8_add(v);
        }
        rs[8] = red8_add((lg == 0) ? coef17 : 0.0f);
        rs[9] = red8_add((lg == 1) ? coef17 : 0.0f);
        v2f rhs2[5];
        {
            const float4* pv4 = (const float4*)(sPV + eidx*12);
            float4 pa = pv4[0], pb = pv4[1];
            const float2* pv2 = (const float2*)(sPV + eidx*12 + 8);
            float2 pc = pv2[0];
            rhs2[0] = make2(-(pa.x + rs[0]), -(pa.y + rs[1]));
            rhs2[1] = make2(-(pa.z + rs[2]), -(pa.w + rs[3]));
            rhs2[2] = make2(-(pb.x + rs[4]), -(pb.y + rs[5]));
            rhs2[3] = make2(-(pb.z + rs[6]), -(pb.w + rs[7]));
            rhs2[4] = make2(-(pc.x + rs[8]), -(pc.y + rs[9]));
        }
        #pragma unroll
        for (int j = 0; j < 10; ++j){
            float4 qa = sQm4[j*3+0], qb = sQm4[j*3+1], qc = sQm4[j*3+2];
            v2f mz = splat2(-z[j]);
            rhs2[0] = pkfma(mz, make2(qa.x, qa.y), rhs2[0]);
            rhs2[1] = pkfma(mz, make2(qa.z, qa.w), rhs2[1]);
            rhs2[2] = pkfma(mz, make2(qb.x, qb.y), rhs2[2]);
            rhs2[3] = pkfma(mz, make2(qb.z, qb.w), rhs2[3]);
            rhs2[4] = pkfma(mz, make2(qc.x, qc.y), rhs2[4]);
            if (j >= 8){
                float qq[10] = {qa.x,qa.y,qa.z,qa.w, qb.x,qb.y,qb.z,qb.w, qc.x,qc.y};
                #pragma unroll
                for (int i = 0; i <= j; ++i) Hm[TIX(j,i)] = qq[i];
            }
        }
        Hm[TIX(8,8)] += d88;
        Hm[TIX(9,9)] += d99;
        float rhs[10] = {rhs2[0].x, rhs2[0].y, rhs2[1].x, rhs2[1].y, rhs2[2].x,
                         rhs2[2].y, rhs2[3].x, rhs2[3].y, rhs2[4].x, rhs2[4].y};
        #pragma unroll
        for (int j = 0; j < 10; ++j){
            float d = Hm[TIX(j,j)];
            #pragma unroll
            for (int k2 = 0; k2 < j; ++k2){ float v = Hm[TIX(j,k2)]; d = fmaf(-v, v, d); }
            d = fmaxf(d, 1e-30f);
            float rinv = frsq(d);
            Hm[TIX(j,j)] = rinv;
            #pragma unroll
            for (int i = j+1; i < 10; ++i){
                float v2 = Hm[TIX(i,j)];
                #pragma unroll
                for (int k2 = 0; k2 < j; ++k2) v2 = fmaf(-Hm[TIX(i,k2)], Hm[TIX(j,k2)], v2);
                Hm[TIX(i,j)] = v2 * rinv;
            }
        }
        #pragma unroll
        for (int i = 0; i < 10; ++i){
            float v2 = rhs[i];
            #pragma unroll
            for (int k2 = 0; k2 < i; ++k2) v2 = fmaf(-Hm[TIX(i,k2)], rhs[k2], v2);
            rhs[i] = v2 * Hm[TIX(i,i)];
        }
        float dz[10];
        #pragma unroll
        for (int i = 9; i >= 0; --i){
            float v2 = rhs[i];
            #pragma unroll
            for (int k2 = i+1; k2 < 10; ++k2) v2 = fmaf(-Hm[TIX(k2,i)], dz[k2], v2);
            dz[i] = v2 * Hm[TIX(i,i)];
        }
        __asm__ __volatile__("" ::: "memory");
        v2f nsmu2 = splat2(-smu);
        v2f ds2[8], dl2[8];
        v2f av2 = splat2(0.0f);
        PSTEPC(0, 2, g0)  PSTEPC(1, 2, g1)
        PSTEPC(2, 4, g2r) PSTEPC(3, 4, g3r)
        PSTEPC(4, 6, g4r) PSTEPC(5, 6, g5r)
        { LOADP(gv, 0) PSTEPC(6, 8, gv) }
        { LOADP(gv, 1) PSTEPC(7, 8, gv) }
        float ds16, dl16, ds17, dl17;
        float ainv = fmaxf(av2.x, av2.y);
        {
            float dzs = dz[0];
            #pragma unroll
            for (int i = 1; i < 8; ++i) dzs = (lg == i) ? dz[i] : dzs;
            float dsk = -rp16 - dzs;
            float isk = frcp(s16v);
            float rc = fmaf(s16v, lam16v, -smu);
            float dlk = -(rc + lam16v * dsk) * isk;
            ds16 = dsk; dl16 = dlk;
            ainv = fmaxf(ainv, fmaxf(-dsk * isk, -dlk * frcp(lam16v)));
        }
        {
            float dzs = (lg == 1) ? dz[9] : dz[8];
            bool val = lg < 2;
            float dsk = val ? (-rp17 - dzs) : 0.0f;
            float isk = frcp(s17v);
            float rc = fmaf(s17v, lam17v, -smu);
            float dlk = -(rc + lam17v * dsk) * isk;
            dlk = val ? dlk : 0.0f;
            ds17 = dsk; dl17 = dlk;
            float cand = fmaxf(-dsk * isk, -dlk * frcp(lam17v));
            ainv = fmaxf(ainv, val ? cand : 0.0f);
        }
        ainv = red8_max(ainv);
        float alpha = fminf(1.0f, 0.99f * frcp(fmaxf(ainv, 1e-30f)));
        v2f al2 = splat2(alpha);
        #pragma unroll
        for (int i = 0; i < 10; ++i) z[i] = fmaf(alpha, dz[i], z[i]);
        #pragma unroll
        for (int p = 0; p < 8; ++p){
            s2[p]   = pkfma(al2, ds2[p], s2[p]);
            lam2[p] = pkfma(al2, dl2[p], lam2[p]);
        }
        s16v   = fmaf(alpha, ds16, s16v);
        s17v   = fmaf(alpha, ds17, s17v);
        lam16v = fmaf(alpha, dl16, lam16v);
        lam17v = fmaf(alpha, dl17, lam17v);
    }
    if (lg == 0) out[elem] = z[0];
}

extern "C" void kernel_launch(void* const* d_in, const int* in_sizes, int n_in,
                              void* d_out, int out_size, void* d_ws, size_t ws_size,
                              hipStream_t stream){
    const float* x   = (const float*)d_in[0];
    const float* w1  = (const float*)d_in[1];
    const float* b1  = (const float*)d_in[2];
    const float* w2  = (const float*)d_in[3];
    const float* b2  = (const float*)d_in[4];
    const float* g1  = (const float*)d_in[5];
    const float* bb1 = (const float*)d_in[6];
    const float* g2  = (const float*)d_in[7];
    const float* bb2 = (const float*)d_in[8];
    const float* L   = (const float*)d_in[9];
    const float* LP  = (const float*)d_in[10];
    const float* LR  = (const float*)d_in[11];
    const float* A   = (const float*)d_in[12];
    const float* Bm  = (const float*)d_in[13];
    const float* u0  = (const float*)d_in[14];
    const float* s0  = (const float*)d_in[15];
    float* ws  = (float*)d_ws;
    float* out = (float*)d_out;

    // zero P2 + P1 partial accumulators (floats 2048..10560)
    hipMemsetAsync(ws + P2_OFF, 0, (P1Q_OFF + 4096 - P2_OFF) * sizeof(float), stream);
    void* kargs[] = { (void*)&x, (void*)&w1, (void*)&w2, (void*)&b1, (void*)&b2,
                      (void*)&g1, (void*)&bb1, (void*)&L, (void*)&LP, (void*)&LR,
                      (void*)&A, (void*)&Bm, (void*)&u0, (void*)&s0, (void*)&ws };
    hipLaunchCooperativeKernel((const void*)k_fused, dim3(256), dim3(1024), kargs, 0, stream);
    hipLaunchKernelGGL(k_ipm, dim3(2048), dim3(64), 0, stream, ws, g2, bb2, out);
}

// Round 11
// 306.268 us; speedup vs baseline: 5.1812x; 5.1812x over previous
//
#include <hip/hip_runtime.h>
#include <math.h>

#define NIx 32
#define NOx 2
#define NUx 10
#define NHx 1024
#define NBx 16384
#define MIx 138
#define EPSQ 1e-4f
#define BNEPS 1e-5f
#define ITERS 30
#define SLOPE 0.2f
#define SIGMA_C 0.1f

// workspace layout (float offsets). Max = 174400 floats = 697.6 KB (< proven 723 KB).
#define QM_OFF 0        // 120 (pad 128)
#define G_OFF 128       // 144 x 12 -> 1856
#define H_OFF 1856      // 144 (pad 2048)
#define P2_OFF 2048     // 16 bufs x 20 (sum[10],sq[10]) = 320 (pad 2368)
#define P1S_OFF 2368    // 4 bufs x 1024 col-sums
#define P1Q_OFF 6464    // 4 bufs x 1024 col-sumsq -> 10560
#define PRAW_OFF 10560  // 16384 x 10 -> 174400
// memset zeroes [P2_OFF, P1Q_OFF+4096) = floats 2048..10560

// ======================= CONFIGURATION LEDGER (rounds 0-10) ======================
// Best measured config = ROUND 5/9 (307.7 / 308.6 us): restored verbatim here.
//   k_ipm:    ~174 us, VALU-issue bound @78%, 128-VGPR envelope (r2 promotion-
//             spill; r8 cap-spill). 8 lanes/elem optimal (r7 analysis).
//   k_fc2:    256 blocks x 1024 thr, 64 rows/block. Reuse law (r6): shrinking
//             rows/block multiplied traffic to 1.4 GB -> HBM-bound. Cap law
//             (r8): (1024,8) crushed VGPR to 32 -> 2.3 GB spill.
//   k_bstats: 2048 BN1 blocks of 32 rows, natural occupancy (r7: 8 blocks/CU
//             forced was -9 us WORSE).
//   FUSION CLOSED (r10): 1024-thr blocks compiler-cap ~64 VGPR -> h[64] spills
//             (2.3 GB WRITE, 4.3x slower); h staging needs 64 MB >> 723 KB ws.
//             Duplicated FC1 GEMM is structurally unavoidable here.
// Laws: occupancy gains only within natural VGPR + without multiplying DRAM
// traffic; v_pk_*_f32 issue-neutral (r1); s_load == LDS-broadcast (r3/r4).
// =================================================================================

__device__ __forceinline__ float frcp(float x){ return __builtin_amdgcn_rcpf(x); }
__device__ __forceinline__ float frsq(float x){ return __builtin_amdgcn_rsqf(x); }
__device__ __forceinline__ float lrelu(float x){ return x > 0.0f ? x : SLOPE * x; }

typedef float v2f __attribute__((ext_vector_type(2)));
__device__ __forceinline__ v2f make2(float a, float b){ v2f r; r.x = a; r.y = b; return r; }
__device__ __forceinline__ v2f splat2(float a){ v2f r; r.x = a; r.y = a; return r; }
__device__ __forceinline__ v2f pkfma(v2f a, v2f b, v2f c){ return __builtin_elementwise_fma(a, b, c); }
__device__ __forceinline__ v2f pkmax(v2f a, v2f b){ return __builtin_elementwise_max(a, b); }

// ---- DPP cross-lane reductions (VALU, no LDS pipe) ----
template<int CTRL>
__device__ __forceinline__ float dpp_mov(float x){
    int y = __builtin_amdgcn_update_dpp(0, __float_as_int(x), CTRL, 0xF, 0xF, true);
    return __int_as_float(y);
}
__device__ __forceinline__ float red8_add(float x){
    x += dpp_mov<0xB1>(x);
    x += dpp_mov<0x4E>(x);
    x += dpp_mov<0x141>(x);
    return x;
}
__device__ __forceinline__ float red8_max(float x){
    x = fmaxf(x, dpp_mov<0xB1>(x));
    x = fmaxf(x, dpp_mov<0x4E>(x));
    x = fmaxf(x, dpp_mov<0x141>(x));
    return x;
}

// ---------- merged: blocks 0..2047 BN1-stats, block 2048 QP-build ----------
__global__ __launch_bounds__(256) void k_buildstats(const float* L, const float* LP, const float* LR,
                                                    const float* A, const float* Bm,
                                                    const float* u0, const float* s0,
                                                    const float* x, const float* w1, const float* b1,
                                                    float* ws){
    __shared__ float sL[1024], sLP[1024], sA[1024], sQ[1024], sP[1024];
    __shared__ float sPow[4][64];
    __shared__ float sBh[128*10];
    __shared__ float sQB[128*10];
    __shared__ float sR[3];
    __shared__ __align__(16) float sX[1024];   // 32 x-rows, 4 KB (BN1 path only)
    int t = threadIdx.x;
    if (blockIdx.x < 2048){
        // ---- BN1 stats path: partial col sum/sumsq into 4 spread buffers ----
        int rb = blockIdx.x >> 2;        // 512 row-groups of 32 rows
        int cb = blockIdx.x & 3;         // 4 col-groups of 256 cols
        int c = cb * 256 + t;
        const float4* wg4 = (const float4*)(w1 + (size_t)c * 32);
        float4 wr[8];
        #pragma unroll
        for (int q = 0; q < 8; ++q) wr[q] = wg4[q];
        float bc = b1[c];
        int r0 = rb * 32;
        // stage x rows r0..r0+31 (coalesced: 256 float4 over 256 threads)
        const float4* xg4 = (const float4*)x + (size_t)r0 * 8;
        float4* sX4 = (float4*)sX;
        sX4[t] = xg4[t];
        __syncthreads();
        float sum = 0.0f, sq = 0.0f;
        #pragma unroll 2
        for (int r = 0; r < 32; ++r){
            const float4* xr4 = sX4 + r * 8;   // wave-uniform -> broadcast ds_read_b128
            float a0 = 0, a1 = 0, a2 = 0, a3 = 0;
            #pragma unroll
            for (int q = 0; q < 8; ++q){
                float4 v = xr4[q];
                a0 = fmaf(v.x, wr[q].x, a0);
                a1 = fmaf(v.y, wr[q].y, a1);
                a2 = fmaf(v.z, wr[q].z, a2);
                a3 = fmaf(v.w, wr[q].w, a3);
            }
            float h = lrelu((a0 + a1) + (a2 + a3) + bc);
            sum += h; sq = fmaf(h, h, sq);
        }
        int buf = (rb & 3) * 1024 + c;
        atomicAdd(&ws[P1S_OFF + buf], sum);
        atomicAdd(&ws[P1Q_OFF + buf], sq);
        return;
    }
    // ---- QP build path (single block, blockIdx 2048) ----
    for (int idx = t; idx < 1024; idx += 256){
        int i = idx >> 5, j = idx & 31;
        sL[idx]  = (j <= i) ? L[idx]  : 0.0f;
        sLP[idx] = (j <= i) ? LP[idx] : 0.0f;
        sA[idx]  = A[idx];
    }
    if (t < 64) sPow[0][t] = Bm[t];
    if (t == 0){
        float a = LR[0], b = LR[2], c = LR[3];   // tril: [[a,0],[b,c]]
        sR[0] = a*a + EPSQ; sR[1] = a*b; sR[2] = b*b + c*c + EPSQ;
    }
    __syncthreads();
    for (int idx = t; idx < 1024; idx += 256){
        int i = idx >> 5, j = idx & 31;
        float q = 0.0f, p = 0.0f;
        for (int k = 0; k < 32; ++k){
            q = fmaf(sL[i*32+k],  sL[j*32+k],  q);
            p = fmaf(sLP[i*32+k], sLP[j*32+k], p);
        }
        if (i == j){ q += EPSQ; p += EPSQ; }
        sQ[idx] = q; sP[idx] = p;
    }
    for (int kp = 1; kp < 4; ++kp){
        __syncthreads();
        if (t < 64){
            int i = t >> 1, c = t & 1;
            float a = 0.0f;
            for (int j = 0; j < 32; ++j) a = fmaf(sA[i*32+j], sPow[kp-1][j*2+c], a);
            sPow[kp][t] = a;
        }
    }
    __syncthreads();
    for (int idx = t; idx < 1280; idx += 256){
        int r = idx / 10, c = idx % 10;
        int bi = r >> 5, ri = r & 31, bj = c >> 1, cj = c & 1;
        sBh[idx] = (bj <= bi) ? sPow[bi-bj][ri*2+cj] : 0.0f;
    }
    __syncthreads();
    for (int idx = t; idx < 1280; idx += 256){
        int r = idx / 10, c = idx % 10;
        int bi = r >> 5, ri = r & 31;
        const float* Qd = (bi < 3) ? sQ : sP;
        float a = 0.0f;
        for (int k = 0; k < 32; ++k) a = fmaf(Qd[ri*32+k], sBh[(bi*32+k)*10+c], a);
        sQB[idx] = a;
    }
    __syncthreads();
    if (t < 120){
        int i = t / 12, j = t % 12;
        float a = 0.0f;
        if (j < 10){
            for (int r = 0; r < 128; ++r) a = fmaf(sBh[r*10+i], sQB[r*10+j], a);
            if ((i >> 1) == (j >> 1)) a += sR[(i&1)+(j&1)];
        }
        ws[QM_OFF + t] = a;
    }
    for (int idx = t; idx < 144*12; idx += 256){
        int m = idx / 12, i = idx % 12;
        float v = 0.0f;
        if (i < 10 && m < MIx) v = (m < 10) ? ((i == m) ? 1.0f : 0.0f) : sBh[(m-10)*10 + i];
        ws[G_OFF + idx] = v;
    }
    for (int m = t; m < 144; m += 256){
        float hv = 0.0f;
        if (m < MIx){
            hv = s0[m];
            if (m < 10) hv += u0[m];
            else { for (int i = 0; i < 10; ++i) hv = fmaf(sBh[(m-10)*10+i], u0[i], hv); }
        }
        ws[H_OFF + m] = hv;
    }
}

// ---------- fc2 with BN1-finalize folded in-block ----------
// 256 blocks x 1024 threads (16 waves = 4 waves/SIMD). 64 rows/block -> full
// w1 reuse. w1 in 16 KB LDS chunks; wave owns an 8-row slice per chunk.
// pacc aliases the chunk buffer (barrier-separated).
__global__ __launch_bounds__(1024) void k_fc2(const float* __restrict__ x, const float* __restrict__ w1,
                                              const float* __restrict__ w2, const float* __restrict__ b1v,
                                              const float* __restrict__ b2v, const float* __restrict__ g1,
                                              const float* __restrict__ bb1, float* __restrict__ ws){
    __shared__ __align__(16) float sPool[10240];  // chunks: sW 4096 floats; after: pacc 10240
    __shared__ float sA1[1024], sC1[1024];
    int t = threadIdx.x;
    if (t < 1024){
        int k = t;
        float ssum = 0.0f, qsum = 0.0f;
        #pragma unroll
        for (int b = 0; b < 4; ++b){
            ssum += ws[P1S_OFF + b*1024 + k];
            qsum += ws[P1Q_OFF + b*1024 + k];
        }
        float mu  = ssum * (1.0f/16384.0f);
        float var = qsum * (1.0f/16384.0f) - mu*mu;
        float a1 = g1[k] / sqrtf(var + BNEPS);
        sA1[k] = a1;
        sC1[k] = bb1[k] - mu * a1;
    }
    int r = t & 63;
    int q = t >> 6;                  // 0..15: wave owns an 8-row slice of each chunk
    int row = blockIdx.x * 64 + r;
    const float4* xg4 = (const float4*)(x + (size_t)row * 32);
    float4 xr[8];
    #pragma unroll
    for (int i = 0; i < 8; ++i) xr[i] = xg4[i];
    float acc[10];
    #pragma unroll
    for (int j = 0; j < 10; ++j) acc[j] = 0.0f;
    const float4* w1g4 = (const float4*)w1;
    float4* sW4 = (float4*)sPool;
    for (int ch = 0; ch < 8; ++ch){
        __syncthreads();   // previous chunk fully consumed (also fences sA1/sC1 on ch=0)
        if (t < 1024) sW4[t] = w1g4[ch*1024 + t];
        __syncthreads();
        #pragma unroll
        for (int i = 0; i < 8; ++i){
            int klc = __builtin_amdgcn_readfirstlane(q*8 + i);       // chunk-local row
            int kl  = __builtin_amdgcn_readfirstlane(ch*128 + klc);  // global k
            const float4* wv4 = sW4 + klc*8;   // wave-uniform -> broadcast ds_read_b128
            float a0 = 0, a1 = 0, a2 = 0, a3 = 0;
            #pragma unroll
            for (int u = 0; u < 8; ++u){
                float4 wv = wv4[u];
                float4 xv = xr[u];
                a0 = fmaf(xv.x, wv.x, a0);
                a1 = fmaf(xv.y, wv.y, a1);
                a2 = fmaf(xv.z, wv.z, a2);
                a3 = fmaf(xv.w, wv.w, a3);
            }
            float h = fmaf(lrelu((a0 + a1) + (a2 + a3) + b1v[kl]), sA1[kl], sC1[kl]);
            #pragma unroll
            for (int j = 0; j < 10; ++j) acc[j] = fmaf(h, w2[j*1024 + kl], acc[j]);
        }
    }
    __syncthreads();   // all waves done with sW before pacc aliases the region
    float* pacc = sPool;
    #pragma unroll
    for (int j = 0; j < 10; ++j) pacc[t*10 + j] = acc[j];
    __syncthreads();
    if (t < 64){
        float pv[10];
        #pragma unroll
        for (int j = 0; j < 10; ++j){
            float a = b2v[j];
            #pragma unroll
            for (int w = 0; w < 16; ++w) a += pacc[(w*64 + t)*10 + j];
            pv[j] = lrelu(a);
        }
        #pragma unroll
        for (int j = 0; j < 10; ++j) ws[PRAW_OFF + (size_t)(blockIdx.x*64 + t)*10 + j] = pv[j];
        float sv[10], qv[10];
        #pragma unroll
        for (int j = 0; j < 10; ++j){ sv[j] = pv[j]; qv[j] = pv[j]*pv[j]; }
        #pragma unroll
        for (int m = 1; m < 64; m <<= 1){
            #pragma unroll
            for (int j = 0; j < 10; ++j){
                sv[j] += __shfl_xor(sv[j], m);
                qv[j] += __shfl_xor(qv[j], m);
            }
        }
        if (t == 0){
            int base = P2_OFF + (blockIdx.x & 15) * 20;
            #pragma unroll
            for (int j = 0; j < 10; ++j){
                atomicAdd(&ws[base + j], sv[j]);
                atomicAdd(&ws[base + 10 + j], qv[j]);
            }
        }
    }
}

// ---------- batched IPM: 8 lanes/element, 8 elements per 64-thread block ----------
#define TIX(i,j) ((i)*((i)+1)/2 + (j))

#define PSTEPA(P, B, GP) { \
    v2f sv = s2[P], lv = lam2[P]; \
    v2f isv; isv.x = frcp(sv.x); isv.y = frcp(sv.y); \
    v2f wv = lv * isv; \
    v2f r = sv - *(const v2f*)(sHH2 + (P)*16 + lg*2); \
    _Pragma("unroll") \
    for (int _i = 0; _i < (B); ++_i) r = pkfma(splat2(z[_i]), GP[_i], r); \
    rp2[P] = r; \
    sl2 = pkfma(sv, lv, sl2); \
    _Pragma("unroll") \
    for (int _i = 0; _i < (B); ++_i){ \
        v2f wg = wv * GP[_i]; \
        _Pragma("unroll") \
        for (int _j = 0; _j <= _i; ++_j) Hm2[TIX(_i,_j)] = pkfma(wg, GP[_j], Hm2[TIX(_i,_j)]); \
    } }

#define PSTEPB(P, B, GP) { \
    v2f sv = s2[P], lv = lam2[P]; \
    v2f isv; isv.x = frcp(sv.x); isv.y = frcp(sv.y); \
    v2f coef = pkfma(lv, rp2[P], smu2) * isv; \
    _Pragma("unroll") \
    for (int _i = 0; _i < (B); ++_i) racc2[_i] = pkfma(coef, GP[_i], racc2[_i]); }

#define PSTEPC(P, B, GP) { \
    v2f dotv = splat2(0.0f); \
    _Pragma("unroll") \
    for (int _i = 0; _i < (B); ++_i) dotv = pkfma(splat2(dz[_i]), GP[_i], dotv); \
    v2f sv = s2[P], lv = lam2[P]; \
    v2f isv; isv.x = frcp(sv.x); isv.y = frcp(sv.y); \
    v2f dsv = -(rp2[P] + dotv); \
    v2f rcv = pkfma(sv, lv, nsmu2); \
    v2f dlv = -(pkfma(lv, dsv, rcv) * isv); \
    ds2[P] = dsv; dl2[P] = dlv; \
    v2f ilv; ilv.x = frcp(lv.x); ilv.y = frcp(lv.y); \
    av2 = pkmax(av2, pkmax((-dsv)*isv, (-dlv)*ilv)); }

#define LOADP(GP, PP) v2f GP[8]; { \
    const float4* _g4 = (const float4*)(sG3 + lg*36 + (PP)*16); \
    float4 _a = _g4[0], _b = _g4[1], _c = _g4[2], _d = _g4[3]; \
    GP[0] = make2(_a.x,_a.y); GP[1] = make2(_a.z,_a.w); \
    GP[2] = make2(_b.x,_b.y); GP[3] = make2(_b.z,_b.w); \
    GP[4] = make2(_c.x,_c.y); GP[5] = make2(_c.z,_c.w); \
    GP[6] = make2(_d.x,_d.y); GP[7] = make2(_d.z,_d.w); }

__global__ __launch_bounds__(64, 2) void k_ipm(const float* __restrict__ ws, const float* __restrict__ g2v,
                                               const float* __restrict__ bb2, float* __restrict__ out){
    __shared__ __align__(16) float sQm[120];
    __shared__ __align__(16) float sQt2[72];    // {Q/8, 0} interleaved, tri rows 0..7
    __shared__ __align__(16) float sPV[8*12];
    __shared__ __align__(16) float sG3[8*36];   // B=8 G pairs, pair-packed per lg
    __shared__ __align__(16) float sHH2[128];   // h pair-packed: [p*16 + lg*2 + c]
    __shared__ float sA2[10], sC2[10];
    int t = threadIdx.x;
    for (int i = t; i < 120; i += 64) sQm[i] = ws[QM_OFF + i];
    if (t < 36){
        int i = 0;
        #pragma unroll
        for (int r = 1; r < 8; ++r) if (TIX(r,0) <= t) i = r;
        int j = t - TIX(i,0);
        sQt2[t*2]   = ws[QM_OFF + i*12 + j] * 0.125f;
        sQt2[t*2+1] = 0.0f;
    }
    if (t < 10){   // BN2 finalize (redundant per block — trivial)
        float ssum = 0.0f, qsum = 0.0f;
        #pragma unroll
        for (int b = 0; b < 16; ++b){
            ssum += ws[P2_OFF + b*20 + t];
            qsum += ws[P2_OFF + b*20 + 10 + t];
        }
        float mu  = ssum * (1.0f/16384.0f);
        float var = qsum * (1.0f/16384.0f) - mu*mu;
        float a2 = g2v[t] / sqrtf(var + BNEPS);
        sA2[t] = a2;
        sC2[t] = bb2[t] - mu * a2;
    }
    __syncthreads();

    int lg = t & 7;
    int eidx = t >> 3;
    int elem = blockIdx.x * 8 + eidx;
    const float* GB = ws + G_OFF;
    const float4* sQm4 = (const float4*)sQm;

    for (int i = t; i < 80; i += 64){
        int e = i / 10, c = i - e*10;
        int el = blockIdx.x * 8 + e;
        sPV[e*12 + c] = fmaf(ws[PRAW_OFF + (size_t)el*10 + c], sA2[c], sC2[c]);
    }
    for (int i = t; i < 128; i += 64){
        int c = i & 1, lgx = (i >> 1) & 7, p = i >> 4;
        int row = 10 + (p >> 1)*32 + (2*(p & 1) + c)*8 + lgx;
        sHH2[p*16 + lgx*2 + c] = ws[H_OFF + row];
    }
    for (int i = t; i < 256; i += 64){
        int c = i & 1, ii = (i >> 1) & 7, pp = (i >> 4) & 1, lgx = i >> 5;
        int row = 106 + (pp*2 + c)*8 + lgx;
        sG3[lgx*36 + pp*16 + ii*2 + c] = GB[row*12 + ii];
    }
    v2f g0[2], g1[2], g2r[4], g3r[4], g4r[6], g5r[6];
    {
        int ra, rb;
        ra = 10 + lg; rb = 18 + lg;
        #pragma unroll
        for (int i = 0; i < 2; ++i) g0[i] = make2(GB[ra*12+i], GB[rb*12+i]);
        ra = 26 + lg; rb = 34 + lg;
        #pragma unroll
        for (int i = 0; i < 2; ++i) g1[i] = make2(GB[ra*12+i], GB[rb*12+i]);
        ra = 42 + lg; rb = 50 + lg;
        #pragma unroll
        for (int i = 0; i < 4; ++i) g2r[i] = make2(GB[ra*12+i], GB[rb*12+i]);
        ra = 58 + lg; rb = 66 + lg;
        #pragma unroll
        for (int i = 0; i < 4; ++i) g3r[i] = make2(GB[ra*12+i], GB[rb*12+i]);
        ra = 74 + lg; rb = 82 + lg;
        #pragma unroll
        for (int i = 0; i < 6; ++i) g4r[i] = make2(GB[ra*12+i], GB[rb*12+i]);
        ra = 90 + lg; rb = 98 + lg;
        #pragma unroll
        for (int i = 0; i < 6; ++i) g5r[i] = make2(GB[ra*12+i], GB[rb*12+i]);
    }
    float h16 = ws[H_OFF + lg];                          // identity rows 0..7
    float h17 = (lg < 2) ? ws[H_OFF + 8 + lg] : 1.0f;    // identity rows 8,9
    __syncthreads();

    float z[10];
    #pragma unroll
    for (int i = 0; i < 10; ++i) z[i] = 0.0f;
    v2f s2[8], lam2[8];
    #pragma unroll
    for (int p = 0; p < 8; ++p){ s2[p] = splat2(1.0f); lam2[p] = splat2(1.0f); }
    float s16v = 1.0f, s17v = 1.0f, lam16v = 1.0f;
    float lam17v = (lg < 2) ? 1.0f : 0.0f;

    #pragma unroll 1
    for (int it = 0; it < ITERS; ++it){
        v2f Hm2[36];
        {
            const v2f* qt2 = (const v2f*)sQt2;
            #pragma unroll
            for (int i = 0; i < 36; ++i) Hm2[i] = qt2[i];   // {Q/8, 0}
        }
        v2f sl2 = splat2(0.0f);
        v2f rp2[8];
        float rp16, rp17;
        PSTEPA(0, 2, g0)  PSTEPA(1, 2, g1)
        PSTEPA(2, 4, g2r) PSTEPA(3, 4, g3r)
        PSTEPA(4, 6, g4r) PSTEPA(5, 6, g5r)
        { LOADP(gv, 0) PSTEPA(6, 8, gv) }
        { LOADP(gv, 1) PSTEPA(7, 8, gv) }
        float w16, w17, sl_s;
        {
            float zs = z[0];
            #pragma unroll
            for (int i = 1; i < 8; ++i) zs = (lg == i) ? z[i] : zs;
            rp16 = zs + s16v - h16;
            sl_s = s16v * lam16v;
            w16 = lam16v * frcp(s16v);
            float zs17 = (lg == 1) ? z[9] : z[8];
            rp17 = zs17 + s17v - h17;
            sl_s = fmaf(s17v, lam17v, sl_s);
            w17 = lam17v * frcp(s17v);
        }
        float Hm[55];
        #pragma unroll
        for (int i = 0; i < 36; ++i) Hm[i] = Hm2[i].x + Hm2[i].y;
        #pragma unroll
        for (int i = 0; i < 8; ++i) Hm[TIX(i,i)] += (lg == i) ? w16 : 0.0f;
        float d88 = (lg == 0) ? w17 : 0.0f;
        float d99 = (lg == 1) ? w17 : 0.0f;
        float sl = sl2.x + sl2.y + sl_s;
        #pragma unroll
        for (int i = 0; i < 36; ++i) Hm[i] = red8_add(Hm[i]);
        d88 = red8_add(d88);
        d99 = red8_add(d99);
        sl = red8_add(sl);
        float smu = SIGMA_C * sl * (1.0f/138.0f);
        __asm__ __volatile__("" ::: "memory");
        v2f smu2 = splat2(smu);
        v2f racc2[8];
        #pragma unroll
        for (int i = 0; i < 8; ++i) racc2[i] = splat2(0.0f);
        PSTEPB(0, 2, g0)  PSTEPB(1, 2, g1)
        PSTEPB(2, 4, g2r) PSTEPB(3, 4, g3r)
        PSTEPB(4, 6, g4r) PSTEPB(5, 6, g5r)
        { LOADP(gv, 0) PSTEPB(6, 8, gv) }
        { LOADP(gv, 1) PSTEPB(7, 8, gv) }
        float coef16 = frcp(s16v) * fmaf(lam16v, rp16, smu);
        float coef17 = frcp(s17v) * fmaf(lam17v, rp17, smu);
        coef17 = (lg < 2) ? coef17 : 0.0f;
        float rs[10];
        #pragma unroll
        for (int i = 0; i < 8; ++i){
            float v = racc2[i].x + racc2[i].y;
            v += (lg == i) ? coef16 : 0.0f;
            rs[i] = red8_add(v);
        }
        rs[8] = red8_add((lg == 0) ? coef17 : 0.0f);
        rs[9] = red8_add((lg == 1) ? coef17 : 0.0f);
        v2f rhs2[5];
        {
            const float4* pv4 = (const float4*)(sPV + eidx*12);
            float4 pa = pv4[0], pb = pv4[1];
            const float2* pv2 = (const float2*)(sPV + eidx*12 + 8);
            float2 pc = pv2[0];
            rhs2[0] = make2(-(pa.x + rs[0]), -(pa.y + rs[1]));
            rhs2[1] = make2(-(pa.z + rs[2]), -(pa.w + rs[3]));
            rhs2[2] = make2(-(pb.x + rs[4]), -(pb.y + rs[5]));
            rhs2[3] = make2(-(pb.z + rs[6]), -(pb.w + rs[7]));
            rhs2[4] = make2(-(pc.x + rs[8]), -(pc.y + rs[9]));
        }
        #pragma unroll
        for (int j = 0; j < 10; ++j){
            float4 qa = sQm4[j*3+0], qb = sQm4[j*3+1], qc = sQm4[j*3+2];
            v2f mz = splat2(-z[j]);
            rhs2[0] = pkfma(mz, make2(qa.x, qa.y), rhs2[0]);
            rhs2[1] = pkfma(mz, make2(qa.z, qa.w), rhs2[1]);
            rhs2[2] = pkfma(mz, make2(qb.x, qb.y), rhs2[2]);
            rhs2[3] = pkfma(mz, make2(qb.z, qb.w), rhs2[3]);
            rhs2[4] = pkfma(mz, make2(qc.x, qc.y), rhs2[4]);
            if (j >= 8){
                float q[10] = {qa.x,qa.y,qa.z,qa.w, qb.x,qb.y,qb.z,qb.w, qc.x,qc.y};
                #pragma unroll
                for (int i = 0; i <= j; ++i) Hm[TIX(j,i)] = q[i];
            }
        }
        Hm[TIX(8,8)] += d88;
        Hm[TIX(9,9)] += d99;
        float rhs[10] = {rhs2[0].x, rhs2[0].y, rhs2[1].x, rhs2[1].y, rhs2[2].x,
                         rhs2[2].y, rhs2[3].x, rhs2[3].y, rhs2[4].x, rhs2[4].y};
        #pragma unroll
        for (int j = 0; j < 10; ++j){
            float d = Hm[TIX(j,j)];
            #pragma unroll
            for (int k2 = 0; k2 < j; ++k2){ float v = Hm[TIX(j,k2)]; d = fmaf(-v, v, d); }
            d = fmaxf(d, 1e-30f);
            float rinv = frsq(d);
            Hm[TIX(j,j)] = rinv;
            #pragma unroll
            for (int i = j+1; i < 10; ++i){
                float v2 = Hm[TIX(i,j)];
                #pragma unroll
                for (int k2 = 0; k2 < j; ++k2) v2 = fmaf(-Hm[TIX(i,k2)], Hm[TIX(j,k2)], v2);
                Hm[TIX(i,j)] = v2 * rinv;
            }
        }
        #pragma unroll
        for (int i = 0; i < 10; ++i){
            float v2 = rhs[i];
            #pragma unroll
            for (int k2 = 0; k2 < i; ++k2) v2 = fmaf(-Hm[TIX(i,k2)], rhs[k2], v2);
            rhs[i] = v2 * Hm[TIX(i,i)];
        }
        float dz[10];
        #pragma unroll
        for (int i = 9; i >= 0; --i){
            float v2 = rhs[i];
            #pragma unroll
            for (int k2 = i+1; k2 < 10; ++k2) v2 = fmaf(-Hm[TIX(k2,i)], dz[k2], v2);
            dz[i] = v2 * Hm[TIX(i,i)];
        }
        __asm__ __volatile__("" ::: "memory");
        v2f nsmu2 = splat2(-smu);
        v2f ds2[8], dl2[8];
        v2f av2 = splat2(0.0f);
        PSTEPC(0, 2, g0)  PSTEPC(1, 2, g1)
        PSTEPC(2, 4, g2r) PSTEPC(3, 4, g3r)
        PSTEPC(4, 6, g4r) PSTEPC(5, 6, g5r)
        { LOADP(gv, 0) PSTEPC(6, 8, gv) }
        { LOADP(gv, 1) PSTEPC(7, 8, gv) }
        float ds16, dl16, ds17, dl17;
        float ainv = fmaxf(av2.x, av2.y);
        {
            float dzs = dz[0];
            #pragma unroll
            for (int i = 1; i < 8; ++i) dzs = (lg == i) ? dz[i] : dzs;
            float dsk = -rp16 - dzs;
            float isk = frcp(s16v);
            float rc = fmaf(s16v, lam16v, -smu);
            float dlk = -(rc + lam16v * dsk) * isk;
            ds16 = dsk; dl16 = dlk;
            ainv = fmaxf(ainv, fmaxf(-dsk * isk, -dlk * frcp(lam16v)));
        }
        {
            float dzs = (lg == 1) ? dz[9] : dz[8];
            bool val = lg < 2;
            float dsk = val ? (-rp17 - dzs) : 0.0f;
            float isk = frcp(s17v);
            float rc = fmaf(s17v, lam17v, -smu);
            float dlk = -(rc + lam17v * dsk) * isk;
            dlk = val ? dlk : 0.0f;
            ds17 = dsk; dl17 = dlk;
            float cand = fmaxf(-dsk * isk, -dlk * frcp(lam17v));
            ainv = fmaxf(ainv, val ? cand : 0.0f);
        }
        ainv = red8_max(ainv);
        float alpha = fminf(1.0f, 0.99f * frcp(fmaxf(ainv, 1e-30f)));
        v2f al2 = splat2(alpha);
        #pragma unroll
        for (int i = 0; i < 10; ++i) z[i] = fmaf(alpha, dz[i], z[i]);
        #pragma unroll
        for (int p = 0; p < 8; ++p){
            s2[p]   = pkfma(al2, ds2[p], s2[p]);
            lam2[p] = pkfma(al2, dl2[p], lam2[p]);
        }
        s16v   = fmaf(alpha, ds16, s16v);
        s17v   = fmaf(alpha, ds17, s17v);
        lam16v = fmaf(alpha, dl16, lam16v);
        lam17v = fmaf(alpha, dl17, lam17v);
    }
    if (lg == 0) out[elem] = z[0];
}

extern "C" void kernel_launch(void* const* d_in, const int* in_sizes, int n_in,
                              void* d_out, int out_size, void* d_ws, size_t ws_size,
                              hipStream_t stream){
    const float* x   = (const float*)d_in[0];
    const float* w1  = (const float*)d_in[1];
    const float* b1  = (const float*)d_in[2];
    const float* w2  = (const float*)d_in[3];
    const float* b2  = (const float*)d_in[4];
    const float* g1  = (const float*)d_in[5];
    const float* bb1 = (const float*)d_in[6];
    const float* g2  = (const float*)d_in[7];
    const float* bb2 = (const float*)d_in[8];
    const float* L   = (const float*)d_in[9];
    const float* LP  = (const float*)d_in[10];
    const float* LR  = (const float*)d_in[11];
    const float* A   = (const float*)d_in[12];
    const float* Bm  = (const float*)d_in[13];
    const float* u0  = (const float*)d_in[14];
    const float* s0  = (const float*)d_in[15];
    float* ws  = (float*)d_ws;
    float* out = (float*)d_out;

    // zero P2 + P1 partial accumulators (floats 2048..10560)
    hipMemsetAsync(ws + P2_OFF, 0, (P1Q_OFF + 4096 - P2_OFF) * sizeof(float), stream);
    hipLaunchKernelGGL(k_buildstats, dim3(2049), dim3(256), 0, stream,
                       L, LP, LR, A, Bm, u0, s0, x, w1, b1, ws);
    hipLaunchKernelGGL(k_fc2, dim3(256), dim3(1024), 0, stream, x, w1, w2, b1, b2, g1, bb1, ws);
    hipLaunchKernelGGL(k_ipm, dim3(2048), dim3(64), 0, stream, ws, g2, bb2, out);
}